// Round 1
// baseline (3525.306 us; speedup 1.0000x reference)
//
#include <hip/hip_runtime.h>

#define NN 100000
#define EE 1600000
#define DH 128
#define DO 16

// ---------------------------------------------------------------------------
// degree / normalization
// ---------------------------------------------------------------------------
__global__ __launch_bounds__(256) void k_init_deg(float* __restrict__ deg) {
    int v = blockIdx.x * 256 + threadIdx.x;
    if (v < NN) deg[v] = 1.0f;   // self-loop contributes 1
}

__global__ __launch_bounds__(256) void k_count(const int* __restrict__ dst,
                                               float* __restrict__ deg) {
    int e = blockIdx.x * 256 + threadIdx.x;
    if (e < EE) atomicAdd(deg + dst[e], 1.0f);
}

__global__ __launch_bounds__(256) void k_rsqrt(float* __restrict__ deg) {
    int v = blockIdx.x * 256 + threadIdx.x;
    if (v < NN) deg[v] = rsqrtf(deg[v]);   // deg >= 1 always
}

// ---------------------------------------------------------------------------
// bias broadcast init: h[v][j] = b[j]  (aggregation accumulates on top)
// ---------------------------------------------------------------------------
template <int DD>
__global__ __launch_bounds__(256) void k_bias(float* __restrict__ h,
                                              const float* __restrict__ b) {
    const long long tot = (long long)NN * DD / 4;
    for (long long i = (long long)blockIdx.x * 256 + threadIdx.x; i < tot;
         i += (long long)gridDim.x * 256) {
        int j = (int)(i & (DD / 4 - 1));
        ((float4*)h)[i] = ((const float4*)b)[j];
    }
}

// ---------------------------------------------------------------------------
// GEMM: out[N,128] = act(in[N,128]) @ W[128,128]  (fp32 VALU, W in LDS)
// each wave: 4 rows, lane covers 2 cols (float2); x loads are wave-uniform
// ---------------------------------------------------------------------------
__device__ __forceinline__ float4 relu4(float4 a) {
    a.x = fmaxf(a.x, 0.f); a.y = fmaxf(a.y, 0.f);
    a.z = fmaxf(a.z, 0.f); a.w = fmaxf(a.w, 0.f);
    return a;
}

template <bool RELU>
__global__ __launch_bounds__(256) void k_gemm128(const float* __restrict__ in,
                                                 const float* __restrict__ W,
                                                 float* __restrict__ out) {
    __shared__ float Wl[DH * DH];
    for (int i = threadIdx.x * 4; i < DH * DH; i += 256 * 4)
        *(float4*)(Wl + i) = *(const float4*)(W + i);
    __syncthreads();

    const int wid  = threadIdx.x >> 6;
    const int lane = threadIdx.x & 63;
    const int gw   = blockIdx.x * 4 + wid;
    const int strd = gridDim.x * 4;

    for (int rb = gw * 4; rb < NN; rb += strd * 4) {
        const int rbu = __builtin_amdgcn_readfirstlane(rb);
        const float* x0 = in + (size_t)rbu * DH;
        float2 acc0 = {0.f, 0.f}, acc1 = {0.f, 0.f};
        float2 acc2 = {0.f, 0.f}, acc3 = {0.f, 0.f};

        for (int k = 0; k < DH; k += 4) {
            float4 a0 = *(const float4*)(x0 + 0 * DH + k);
            float4 a1 = *(const float4*)(x0 + 1 * DH + k);
            float4 a2 = *(const float4*)(x0 + 2 * DH + k);
            float4 a3 = *(const float4*)(x0 + 3 * DH + k);
            if (RELU) { a0 = relu4(a0); a1 = relu4(a1); a2 = relu4(a2); a3 = relu4(a3); }

            float2 w0 = *(const float2*)(Wl + (k + 0) * DH + lane * 2);
            float2 w1 = *(const float2*)(Wl + (k + 1) * DH + lane * 2);
            float2 w2 = *(const float2*)(Wl + (k + 2) * DH + lane * 2);
            float2 w3 = *(const float2*)(Wl + (k + 3) * DH + lane * 2);

            acc0.x = fmaf(a0.x, w0.x, acc0.x); acc0.y = fmaf(a0.x, w0.y, acc0.y);
            acc0.x = fmaf(a0.y, w1.x, acc0.x); acc0.y = fmaf(a0.y, w1.y, acc0.y);
            acc0.x = fmaf(a0.z, w2.x, acc0.x); acc0.y = fmaf(a0.z, w2.y, acc0.y);
            acc0.x = fmaf(a0.w, w3.x, acc0.x); acc0.y = fmaf(a0.w, w3.y, acc0.y);

            acc1.x = fmaf(a1.x, w0.x, acc1.x); acc1.y = fmaf(a1.x, w0.y, acc1.y);
            acc1.x = fmaf(a1.y, w1.x, acc1.x); acc1.y = fmaf(a1.y, w1.y, acc1.y);
            acc1.x = fmaf(a1.z, w2.x, acc1.x); acc1.y = fmaf(a1.z, w2.y, acc1.y);
            acc1.x = fmaf(a1.w, w3.x, acc1.x); acc1.y = fmaf(a1.w, w3.y, acc1.y);

            acc2.x = fmaf(a2.x, w0.x, acc2.x); acc2.y = fmaf(a2.x, w0.y, acc2.y);
            acc2.x = fmaf(a2.y, w1.x, acc2.x); acc2.y = fmaf(a2.y, w1.y, acc2.y);
            acc2.x = fmaf(a2.z, w2.x, acc2.x); acc2.y = fmaf(a2.z, w2.y, acc2.y);
            acc2.x = fmaf(a2.w, w3.x, acc2.x); acc2.y = fmaf(a2.w, w3.y, acc2.y);

            acc3.x = fmaf(a3.x, w0.x, acc3.x); acc3.y = fmaf(a3.x, w0.y, acc3.y);
            acc3.x = fmaf(a3.y, w1.x, acc3.x); acc3.y = fmaf(a3.y, w1.y, acc3.y);
            acc3.x = fmaf(a3.z, w2.x, acc3.x); acc3.y = fmaf(a3.z, w2.y, acc3.y);
            acc3.x = fmaf(a3.w, w3.x, acc3.x); acc3.y = fmaf(a3.w, w3.y, acc3.y);
        }
        *(float2*)(out + (size_t)(rbu + 0) * DH + lane * 2) = acc0;
        *(float2*)(out + (size_t)(rbu + 1) * DH + lane * 2) = acc1;
        *(float2*)(out + (size_t)(rbu + 2) * DH + lane * 2) = acc2;
        *(float2*)(out + (size_t)(rbu + 3) * DH + lane * 2) = acc3;
    }
}

// ---------------------------------------------------------------------------
// GEMM: out[N,16] = relu(in[N,128]) @ W[128,16]
// lane = (rsub, col): 4 rows x 16 cols per wave
// ---------------------------------------------------------------------------
template <bool RELU>
__global__ __launch_bounds__(256) void k_gemm16(const float* __restrict__ in,
                                                const float* __restrict__ W,
                                                float* __restrict__ out) {
    __shared__ float Wl[DH * DO];
    for (int i = threadIdx.x * 4; i < DH * DO; i += 256 * 4)
        *(float4*)(Wl + i) = *(const float4*)(W + i);
    __syncthreads();

    const int lane = threadIdx.x & 63;
    const int col  = lane & 15;
    const int rsub = lane >> 4;
    const int gw   = blockIdx.x * 4 + (threadIdx.x >> 6);
    const int strd = gridDim.x * 4;

    for (int rb = gw * 4; rb < NN; rb += strd * 4) {
        int row = rb + rsub;
        const float* x0 = in + (size_t)row * DH;
        float acc = 0.f;
        for (int k = 0; k < DH; k += 4) {
            float4 a = *(const float4*)(x0 + k);
            if (RELU) a = relu4(a);
            acc = fmaf(a.x, Wl[(k + 0) * DO + col], acc);
            acc = fmaf(a.y, Wl[(k + 1) * DO + col], acc);
            acc = fmaf(a.z, Wl[(k + 2) * DO + col], acc);
            acc = fmaf(a.w, Wl[(k + 3) * DO + col], acc);
        }
        out[(size_t)row * DO + col] = acc;
    }
}

// ---------------------------------------------------------------------------
// aggregation D=128: one wave per edge (incl. implicit self-loops e>=EE),
// gather msg[src]*norm, atomic scatter into out[dst]. out pre-seeded with bias.
// ---------------------------------------------------------------------------
__global__ __launch_bounds__(256) void k_agg128(const float* __restrict__ msg,
                                                const int* __restrict__ ei,
                                                const float* __restrict__ dis,
                                                float* __restrict__ out) {
    const int wid  = threadIdx.x >> 6;
    const int lane = threadIdx.x & 63;
    const int tot  = EE + NN;
    for (int e = blockIdx.x * 4 + wid; e < tot; e += gridDim.x * 4) {
        const int eu = __builtin_amdgcn_readfirstlane(e);
        int s, d;
        if (eu < EE) { s = ei[eu]; d = ei[EE + eu]; }
        else         { s = eu - EE; d = s; }
        const float nrm = dis[s] * dis[d];
        float2 v = *(const float2*)(msg + (size_t)s * DH + lane * 2);
        float* op = out + (size_t)d * DH + lane * 2;
        atomicAdd(op,     v.x * nrm);
        atomicAdd(op + 1, v.y * nrm);
    }
}

// ---------------------------------------------------------------------------
// aggregation D=16: 8 lanes per edge (float2 each)
// ---------------------------------------------------------------------------
__global__ __launch_bounds__(256) void k_agg16(const float* __restrict__ msg,
                                               const int* __restrict__ ei,
                                               const float* __restrict__ dis,
                                               float* __restrict__ out) {
    const long long tot = (long long)(EE + NN) * 8;
    for (long long i = (long long)blockIdx.x * 256 + threadIdx.x; i < tot;
         i += (long long)gridDim.x * 256) {
        int e = (int)(i >> 3);
        int l = (int)(i & 7);
        int s, d;
        if (e < EE) { s = ei[e]; d = ei[EE + e]; }
        else        { s = e - EE; d = s; }
        const float nrm = dis[s] * dis[d];
        float2 v = *(const float2*)(msg + (size_t)s * DO + l * 2);
        float* op = out + (size_t)d * DO + l * 2;
        atomicAdd(op,     v.x * nrm);
        atomicAdd(op + 1, v.y * nrm);
    }
}

// ---------------------------------------------------------------------------
extern "C" void kernel_launch(void* const* d_in, const int* in_sizes, int n_in,
                              void* d_out, int out_size, void* d_ws, size_t ws_size,
                              hipStream_t stream) {
    (void)in_sizes; (void)n_in; (void)out_size; (void)ws_size;
    const float* x  = (const float*)d_in[0];
    const int*   ei = (const int*)d_in[1];
    const float* W1 = (const float*)d_in[2];
    const float* b1 = (const float*)d_in[3];
    const float* W2 = (const float*)d_in[4];
    const float* b2 = (const float*)d_in[5];
    const float* W3 = (const float*)d_in[6];
    const float* b3 = (const float*)d_in[7];
    float* out = (float*)d_out;

    float* ws  = (float*)d_ws;
    float* dis = ws;                                // NN floats (deg -> rsqrt)
    float* A   = ws + 100352;                       // NN*128
    float* B   = A + (size_t)NN * DH;               // NN*128
    float* C   = B + (size_t)NN * DH;               // NN*16

    // normalization: deg = 1 + indeg; dis = rsqrt(deg)
    k_init_deg<<<(NN + 255) / 256, 256, 0, stream>>>(dis);
    k_count<<<(EE + 255) / 256, 256, 0, stream>>>(ei + EE, dis);
    k_rsqrt<<<(NN + 255) / 256, 256, 0, stream>>>(dis);

    // layer 1: A = x@W1 ; B = b1 + agg(A)        (relu deferred to next gemm)
    k_gemm128<false><<<6250, 256, 0, stream>>>(x, W1, A);
    k_bias<DH><<<4096, 256, 0, stream>>>(B, b1);
    k_agg128<<<8192, 256, 0, stream>>>(A, ei, dis, B);

    // layer 2: A = relu(B)@W2 ; B = b2 + agg(A)
    k_gemm128<true><<<6250, 256, 0, stream>>>(B, W2, A);
    k_bias<DH><<<4096, 256, 0, stream>>>(B, b2);
    k_agg128<<<8192, 256, 0, stream>>>(A, ei, dis, B);

    // layer 3: C = relu(B)@W3 ; out = b3 + agg(C)
    k_gemm16<true><<<6250, 256, 0, stream>>>(B, W3, C);
    k_bias<DO><<<512, 256, 0, stream>>>(out, b3);
    k_agg16<<<8192, 256, 0, stream>>>(C, ei, dis, out);
}

// Round 4
// 915.861 us; speedup vs baseline: 3.8492x; 3.8492x over previous
//
#include <hip/hip_runtime.h>

#define NN 100000
#define EE 1600000
#define DH 128
#define DO 16
#define NBLK1 98            // ceil(NN/1024)

// ---------------------------------------------------------------------------
// CSR build into ONE cursor array `meta`:
//   zero -> hist (meta[v]=indeg) -> scan (meta[v]=exclusive prefix) ->
//   scatter (meta[v] ends at segment end). Afterwards:
//   end(v)=meta[v], beg(v)=v? meta[v-1]:0, deg(v)=end-beg+1 (self-loop).
// ---------------------------------------------------------------------------
__global__ __launch_bounds__(256) void k_zero(int* __restrict__ meta) {
    int v = blockIdx.x * 256 + threadIdx.x;
    if (v < NN) meta[v] = 0;
}

__global__ __launch_bounds__(256) void k_hist(const int* __restrict__ dst,
                                              int* __restrict__ meta) {
    int e = blockIdx.x * 256 + threadIdx.x;
    if (e < EE) atomicAdd(meta + dst[e], 1);
}

// in-place block-exclusive prefix (Hillis-Steele, double-barrier) + block sums
__global__ __launch_bounds__(1024) void k_scan1(int* __restrict__ meta,
                                                int* __restrict__ bsum) {
    __shared__ int sm[1024];
    const int t = threadIdx.x;
    const int idx = blockIdx.x * 1024 + t;
    int c = (idx < NN) ? meta[idx] : 0;
    int v = c;
    sm[t] = v;
    __syncthreads();
    for (int off = 1; off < 1024; off <<= 1) {
        int add = (t >= off) ? sm[t - off] : 0;
        __syncthreads();
        v += add;
        sm[t] = v;
        __syncthreads();
    }
    if (t == 1023) bsum[blockIdx.x] = v;
    if (idx < NN) meta[idx] = v - c;   // exclusive within block
}

// exclusive scan of the 98 block sums (one 128-thread block)
__global__ __launch_bounds__(128) void k_scan2(int* __restrict__ bsum) {
    __shared__ int sm[128];
    const int t = threadIdx.x;
    int c = (t < NBLK1) ? bsum[t] : 0;
    int v = c;
    sm[t] = v;
    __syncthreads();
    for (int off = 1; off < 128; off <<= 1) {
        int add = (t >= off) ? sm[t - off] : 0;
        __syncthreads();
        v += add;
        sm[t] = v;
        __syncthreads();
    }
    if (t < NBLK1) bsum[t] = v - c;    // exclusive block offsets
}

__global__ __launch_bounds__(256) void k_scan3(int* __restrict__ meta,
                                               const int* __restrict__ bsum) {
    int idx = blockIdx.x * 256 + threadIdx.x;
    if (idx < NN) meta[idx] += bsum[idx >> 10];
}

__global__ __launch_bounds__(256) void k_scatter(const int* __restrict__ ei,
                                                 int* __restrict__ meta,
                                                 int* __restrict__ cs) {
    int e = blockIdx.x * 256 + threadIdx.x;
    if (e < EE) {
        int d = ei[EE + e];
        int pos = atomicAdd(meta + d, 1);
        cs[pos] = ei[e];
    }
}

// ---------------------------------------------------------------------------
// GEMM128: out[r] = dis[r] * ( act(in[r]) @ W )   (fp32 VALU, W in LDS)
// pre-scaling by dis[src] means aggregation is a plain unweighted row-sum.
// ---------------------------------------------------------------------------
__device__ __forceinline__ float4 relu4(float4 a) {
    a.x = fmaxf(a.x, 0.f); a.y = fmaxf(a.y, 0.f);
    a.z = fmaxf(a.z, 0.f); a.w = fmaxf(a.w, 0.f);
    return a;
}

template <bool RELU>
__global__ __launch_bounds__(256) void k_gemm128(const float* __restrict__ in,
                                                 const float* __restrict__ W,
                                                 const int* __restrict__ meta,
                                                 float* __restrict__ out) {
    __shared__ float Wl[DH * DH];
    for (int i = threadIdx.x * 4; i < DH * DH; i += 256 * 4)
        *(float4*)(Wl + i) = *(const float4*)(W + i);
    __syncthreads();

    const int wid  = threadIdx.x >> 6;
    const int lane = threadIdx.x & 63;
    const int gw   = blockIdx.x * 4 + wid;
    const int strd = gridDim.x * 4;

    for (int rb = gw * 4; rb < NN; rb += strd * 4) {
        const int rbu = __builtin_amdgcn_readfirstlane(rb);
        const float* x0 = in + (size_t)rbu * DH;
        float2 acc0 = {0.f, 0.f}, acc1 = {0.f, 0.f};
        float2 acc2 = {0.f, 0.f}, acc3 = {0.f, 0.f};

        for (int k = 0; k < DH; k += 4) {
            float4 a0 = *(const float4*)(x0 + 0 * DH + k);
            float4 a1 = *(const float4*)(x0 + 1 * DH + k);
            float4 a2 = *(const float4*)(x0 + 2 * DH + k);
            float4 a3 = *(const float4*)(x0 + 3 * DH + k);
            if (RELU) { a0 = relu4(a0); a1 = relu4(a1); a2 = relu4(a2); a3 = relu4(a3); }

            float2 w0 = *(const float2*)(Wl + (k + 0) * DH + lane * 2);
            float2 w1 = *(const float2*)(Wl + (k + 1) * DH + lane * 2);
            float2 w2 = *(const float2*)(Wl + (k + 2) * DH + lane * 2);
            float2 w3 = *(const float2*)(Wl + (k + 3) * DH + lane * 2);

            acc0.x = fmaf(a0.x, w0.x, acc0.x); acc0.y = fmaf(a0.x, w0.y, acc0.y);
            acc0.x = fmaf(a0.y, w1.x, acc0.x); acc0.y = fmaf(a0.y, w1.y, acc0.y);
            acc0.x = fmaf(a0.z, w2.x, acc0.x); acc0.y = fmaf(a0.z, w2.y, acc0.y);
            acc0.x = fmaf(a0.w, w3.x, acc0.x); acc0.y = fmaf(a0.w, w3.y, acc0.y);

            acc1.x = fmaf(a1.x, w0.x, acc1.x); acc1.y = fmaf(a1.x, w0.y, acc1.y);
            acc1.x = fmaf(a1.y, w1.x, acc1.x); acc1.y = fmaf(a1.y, w1.y, acc1.y);
            acc1.x = fmaf(a1.z, w2.x, acc1.x); acc1.y = fmaf(a1.z, w2.y, acc1.y);
            acc1.x = fmaf(a1.w, w3.x, acc1.x); acc1.y = fmaf(a1.w, w3.y, acc1.y);

            acc2.x = fmaf(a2.x, w0.x, acc2.x); acc2.y = fmaf(a2.x, w0.y, acc2.y);
            acc2.x = fmaf(a2.y, w1.x, acc2.x); acc2.y = fmaf(a2.y, w1.y, acc2.y);
            acc2.x = fmaf(a2.z, w2.x, acc2.x); acc2.y = fmaf(a2.z, w2.y, acc2.y);
            acc2.x = fmaf(a2.w, w3.x, acc2.x); acc2.y = fmaf(a2.w, w3.y, acc2.y);

            acc3.x = fmaf(a3.x, w0.x, acc3.x); acc3.y = fmaf(a3.x, w0.y, acc3.y);
            acc3.x = fmaf(a3.y, w1.x, acc3.x); acc3.y = fmaf(a3.y, w1.y, acc3.y);
            acc3.x = fmaf(a3.z, w2.x, acc3.x); acc3.y = fmaf(a3.z, w2.y, acc3.y);
            acc3.x = fmaf(a3.w, w3.x, acc3.x); acc3.y = fmaf(a3.w, w3.y, acc3.y);
        }

        // epilogue: pre-scale row r by dis[r] = 1/sqrt(deg[r])
        const int b0 = (rbu == 0) ? 0 : meta[rbu - 1];
        const int e0 = meta[rbu + 0];
        const int e1 = meta[rbu + 1];
        const int e2 = meta[rbu + 2];
        const int e3 = meta[rbu + 3];
        const float d0 = 1.0f / sqrtf((float)(e0 - b0 + 1));
        const float d1 = 1.0f / sqrtf((float)(e1 - e0 + 1));
        const float d2 = 1.0f / sqrtf((float)(e2 - e1 + 1));
        const float d3 = 1.0f / sqrtf((float)(e3 - e2 + 1));
        acc0.x *= d0; acc0.y *= d0;
        acc1.x *= d1; acc1.y *= d1;
        acc2.x *= d2; acc2.y *= d2;
        acc3.x *= d3; acc3.y *= d3;

        *(float2*)(out + (size_t)(rbu + 0) * DH + lane * 2) = acc0;
        *(float2*)(out + (size_t)(rbu + 1) * DH + lane * 2) = acc1;
        *(float2*)(out + (size_t)(rbu + 2) * DH + lane * 2) = acc2;
        *(float2*)(out + (size_t)(rbu + 3) * DH + lane * 2) = acc3;
    }
}

// ---------------------------------------------------------------------------
// GEMM16: out[r] = dis[r] * ( relu(in[r]) @ W[128,16] )
// ---------------------------------------------------------------------------
template <bool RELU>
__global__ __launch_bounds__(256) void k_gemm16(const float* __restrict__ in,
                                                const float* __restrict__ W,
                                                const int* __restrict__ meta,
                                                float* __restrict__ out) {
    __shared__ float Wl[DH * DO];
    for (int i = threadIdx.x * 4; i < DH * DO; i += 256 * 4)
        *(float4*)(Wl + i) = *(const float4*)(W + i);
    __syncthreads();

    const int lane = threadIdx.x & 63;
    const int col  = lane & 15;
    const int rsub = lane >> 4;
    const int gw   = blockIdx.x * 4 + (threadIdx.x >> 6);
    const int strd = gridDim.x * 4;

    for (int rb = gw * 4; rb < NN; rb += strd * 4) {
        int row = rb + rsub;
        const float* x0 = in + (size_t)row * DH;
        float acc = 0.f;
        for (int k = 0; k < DH; k += 4) {
            float4 a = *(const float4*)(x0 + k);
            if (RELU) a = relu4(a);
            acc = fmaf(a.x, Wl[(k + 0) * DO + col], acc);
            acc = fmaf(a.y, Wl[(k + 1) * DO + col], acc);
            acc = fmaf(a.z, Wl[(k + 2) * DO + col], acc);
            acc = fmaf(a.w, Wl[(k + 3) * DO + col], acc);
        }
        const int e  = meta[row];
        const int bg = (row == 0) ? 0 : meta[row - 1];
        const float dl = 1.0f / sqrtf((float)(e - bg + 1));
        out[(size_t)row * DO + col] = acc * dl;
    }
}

// ---------------------------------------------------------------------------
// agg128: one wave per dst node; msg rows are PRE-SCALED by dis[src], so the
// gather is a plain row sum. Edge ids read wave-uniform (no shfl), 4x unroll.
// out[d] = b + dis[d] * ( msg[d] + sum_{s in N(d)} msg[s] )
// ---------------------------------------------------------------------------
__global__ __launch_bounds__(256) void k_agg128(const float* __restrict__ msg,
                                                const int* __restrict__ meta,
                                                const int* __restrict__ cs,
                                                const float* __restrict__ b,
                                                float* __restrict__ out) {
    const int wid  = threadIdx.x >> 6;
    const int lane = threadIdx.x & 63;
    const float2 bb = *(const float2*)(b + lane * 2);
    const int d = blockIdx.x * 4 + wid;
    if (d >= NN) return;
    const int du  = __builtin_amdgcn_readfirstlane(d);
    const int end = meta[du];
    const int beg = (du == 0) ? 0 : meta[du - 1];
    const float dd = 1.0f / sqrtf((float)(end - beg + 1));

    float2 acc = *((const float2*)(msg + (size_t)du * DH) + lane);  // self term

    int j = beg;
    for (; j + 4 <= end; j += 4) {
        int s0 = cs[j], s1 = cs[j + 1], s2 = cs[j + 2], s3 = cs[j + 3];
        float2 v0 = *((const float2*)(msg + (size_t)s0 * DH) + lane);
        float2 v1 = *((const float2*)(msg + (size_t)s1 * DH) + lane);
        float2 v2 = *((const float2*)(msg + (size_t)s2 * DH) + lane);
        float2 v3 = *((const float2*)(msg + (size_t)s3 * DH) + lane);
        acc.x += (v0.x + v1.x) + (v2.x + v3.x);
        acc.y += (v0.y + v1.y) + (v2.y + v3.y);
    }
    for (; j < end; ++j) {
        int s0 = cs[j];
        float2 v0 = *((const float2*)(msg + (size_t)s0 * DH) + lane);
        acc.x += v0.x; acc.y += v0.y;
    }
    float2 o; o.x = bb.x + dd * acc.x; o.y = bb.y + dd * acc.y;
    *((float2*)(out + (size_t)du * DH) + lane) = o;
}

// ---------------------------------------------------------------------------
// agg16: one thread per output element (NN*16)
// ---------------------------------------------------------------------------
__global__ __launch_bounds__(256) void k_agg16(const float* __restrict__ msg,
                                               const int* __restrict__ meta,
                                               const int* __restrict__ cs,
                                               const float* __restrict__ b,
                                               float* __restrict__ out) {
    int i = blockIdx.x * 256 + threadIdx.x;
    if (i >= NN * DO) return;
    const int v   = i >> 4;
    const int col = i & 15;
    const int end = meta[v];
    const int beg = (v == 0) ? 0 : meta[v - 1];
    const float dd = 1.0f / sqrtf((float)(end - beg + 1));

    float acc = msg[(size_t)v * DO + col];   // self term (pre-scaled)
    int j = beg;
    for (; j + 4 <= end; j += 4) {
        int s0 = cs[j], s1 = cs[j + 1], s2 = cs[j + 2], s3 = cs[j + 3];
        acc += (msg[(size_t)s0 * DO + col] + msg[(size_t)s1 * DO + col])
             + (msg[(size_t)s2 * DO + col] + msg[(size_t)s3 * DO + col]);
    }
    for (; j < end; ++j) acc += msg[(size_t)cs[j] * DO + col];
    out[i] = b[col] + dd * acc;
}

// ---------------------------------------------------------------------------
extern "C" void kernel_launch(void* const* d_in, const int* in_sizes, int n_in,
                              void* d_out, int out_size, void* d_ws, size_t ws_size,
                              hipStream_t stream) {
    (void)in_sizes; (void)n_in; (void)out_size; (void)ws_size;
    const float* x  = (const float*)d_in[0];
    const int*   ei = (const int*)d_in[1];
    const float* W1 = (const float*)d_in[2];
    const float* b1 = (const float*)d_in[3];
    const float* W2 = (const float*)d_in[4];
    const float* b2 = (const float*)d_in[5];
    const float* W3 = (const float*)d_in[6];
    const float* b3 = (const float*)d_in[7];
    float* out = (float*)d_out;

    // workspace: 100000 + 128 + 1600000 + 12.8M + 12.8M ints/floats
    //          = 109,200,512 B  (<= 109,201,408 B used by the R0 kernel that
    //            passed validation — stays under the proven ws_size bound)
    int*   meta = (int*)d_ws;              // [NN]  cursor/end-offset array
    int*   baux = meta + NN;               // [128] block sums
    int*   cs   = baux + 128;              // [EE]  CSR src ids
    float* A    = (float*)(cs + EE);       // [NN*DH] pre-scaled messages
    float* B    = A + (size_t)NN * DH;     // [NN*DH] layer outputs
    float* C    = A;                       // alias: layer-3 msg (A dead then)

    // ---- CSR build ----
    k_zero   <<<391, 256, 0, stream>>>(meta);
    k_hist   <<<6250, 256, 0, stream>>>(ei + EE, meta);
    k_scan1  <<<NBLK1, 1024, 0, stream>>>(meta, baux);
    k_scan2  <<<1, 128, 0, stream>>>(baux);
    k_scan3  <<<391, 256, 0, stream>>>(meta, baux);
    k_scatter<<<6250, 256, 0, stream>>>(ei, meta, cs);

    // ---- layer 1: A = dis*(x@W1) ; B = b1 + dis*rowsum(A) ----
    k_gemm128<false><<<6250, 256, 0, stream>>>(x, W1, meta, A);
    k_agg128<<<25000, 256, 0, stream>>>(A, meta, cs, b1, B);

    // ---- layer 2: A = dis*(relu(B)@W2) ; B = b2 + dis*rowsum(A) ----
    k_gemm128<true><<<6250, 256, 0, stream>>>(B, W2, meta, A);
    k_agg128<<<25000, 256, 0, stream>>>(A, meta, cs, b2, B);

    // ---- layer 3: C = dis*(relu(B)@W3) ; out = b3 + dis*rowsum(C) ----
    k_gemm16<true><<<6250, 256, 0, stream>>>(B, W3, meta, C);
    k_agg16<<<6250, 256, 0, stream>>>(C, meta, cs, b3, out);
}